// Round 1
// baseline (580.211 us; speedup 1.0000x reference)
//
#include <hip/hip_runtime.h>
#include <hip/hip_bf16.h>

// Attention4DDownsample — fused, one workgroup per batch element.
// R5 restructure: barrier count 29 -> 5.
//  - mega-phase: kGEMM + qGEMM + full vGEMM (both 256-ch halves) with acc in regs
//  - v-path (vsm write -> v_local -> PV) is wave-private per 32-channel slice: NO barriers
//  - vsm (8 x [32][72]) overlays dead xs region after the mega barrier
//  - P0 staging emits ds_write_b128 (was 32-way-conflicted scalar u16 writes)
//  - attnS XOR-swizzled (nk ^ (nq&7)<<3): PV read conflict 16-way -> 2-way

#define DIMC 384
#define NPOS 49
#define NHKD 128
#define DHC  512
#define OUTC 384

// ws bf16 weight offsets (elements)
#define OFF_KW  0
#define OFF_VW  49152
#define OFF_QPW 245760
#define OFF_PW  294912
#define W_TOT   491520

// LDS regions (bf16 element offsets), total 40840 elems = 81680 B (2 blocks/CU)
#define XS_OFF 0       // xs [49][392] (P0..mega); then vsm 8 x [32][72] (wave-private)
#define R0_OFF 19208   // kt [n][136] rows<49 written -> rout [16][520]
#define R1_OFF 27528   // qsm [8][16][40]
#define R2_OFF 32648   // qin [16][392] -> attnS [8][16][64] XOR-swizzled
#define SMEM_ELEMS 40840

typedef __attribute__((ext_vector_type(8))) __bf16 bf16x8;
typedef __attribute__((ext_vector_type(4))) float f32x4;

static __device__ __forceinline__ __hip_bfloat16 f2b(float x) { return __float2bfloat16(x); }
static __device__ __forceinline__ float b2f(__hip_bfloat16 x) { return __bfloat162float(x); }
static __device__ __forceinline__ bf16x8 ld8(const __hip_bfloat16* p) { return *(const bf16x8*)p; }
static __device__ __forceinline__ f32x4 fzero() {
  f32x4 z; z[0] = 0.f; z[1] = 0.f; z[2] = 0.f; z[3] = 0.f; return z;
}
static __device__ __forceinline__ bf16x8 bzero() {
  bf16x8 z;
  #pragma unroll
  for (int j = 0; j < 8; ++j) z[j] = (__bf16)0.0f;
  return z;
}

// y = conv_out * s + o  implements BN(conv_out + convb)
static __device__ __forceinline__ void bn_so(const float* bn, int C, int ch,
                                             float convb, float& s, float& o) {
  float g  = bn[ch];
  float be = bn[C + ch];
  float mu = bn[2*C + ch];
  float va = bn[3*C + ch];
  s = g * rsqrtf(va + 1e-5f);
  o = be + (convb - mu) * s;
}

// ---------------- prep: fp32 weights -> bf16 in ws ----------------
__global__ void prep_weights(const float* __restrict__ kw, const float* __restrict__ vw,
                             const float* __restrict__ qpw, const float* __restrict__ pw,
                             __hip_bfloat16* __restrict__ wsb) {
  for (int i = blockIdx.x * blockDim.x + threadIdx.x; i < W_TOT; i += gridDim.x * blockDim.x) {
    float v;
    if (i < OFF_VW)       v = kw[i - OFF_KW];
    else if (i < OFF_QPW) v = vw[i - OFF_VW];
    else if (i < OFF_PW)  v = qpw[i - OFF_QPW];
    else                  v = pw[i - OFF_PW];
    wsb[i] = f2b(v);
  }
}

// ---------------- main fused kernel ----------------
__global__ __launch_bounds__(512, 4) void attn4d_kernel(
    const float* __restrict__ x,
    const float* __restrict__ qlw, const float* __restrict__ qlb,
    const float* __restrict__ qpb, const float* __restrict__ qbn,
    const float* __restrict__ kb,  const float* __restrict__ kbn,
    const float* __restrict__ vb,  const float* __restrict__ vbn,
    const float* __restrict__ vlw, const float* __restrict__ vlb,
    const float* __restrict__ vlbn,
    const float* __restrict__ pb,  const float* __restrict__ pbn,
    const float* __restrict__ ab,  const int* __restrict__ bidx,
    const __hip_bfloat16* __restrict__ wsb,
    int n_off, float* __restrict__ out)
{
  __shared__ __align__(16) __hip_bfloat16 smem[SMEM_ELEMS];
  __hip_bfloat16* xs    = smem + XS_OFF;
  __hip_bfloat16* vsm   = smem + XS_OFF;   // overlays xs after mega barrier
  __hip_bfloat16* kt    = smem + R0_OFF;   // [n][136], rows<49 written
  __hip_bfloat16* rout  = smem + R0_OFF;   // [nq][520] overlays kt after PD
  __hip_bfloat16* qsm   = smem + R1_OFF;   // [h][nq][40], kd16..31 zeroed
  __hip_bfloat16* qin   = smem + R2_OFF;   // [16][392]
  __hip_bfloat16* attnS = smem + R2_OFF;   // [h][nq][64] swizzled, overlays qin

  const __hip_bfloat16* kwb  = wsb + OFF_KW;
  const __hip_bfloat16* vwb  = wsb + OFF_VW;
  const __hip_bfloat16* qpwb = wsb + OFF_QPW;
  const __hip_bfloat16* pwb  = wsb + OFF_PW;

  const int tid  = threadIdx.x;
  const int lane = tid & 63;
  const int wave = tid >> 6;     // 0..7
  const int quad = lane >> 4;    // 0..3
  const int l15  = lane & 15;
  const int b    = blockIdx.x;

  // ---- P0: stage x[b] (fp32 global) -> xs[n][c] bf16 transposed, b128 LDS writes
  {
    const float* xg = x + (size_t)b * (DIMC * NPOS);
    for (int j = tid; j < NPOS * (DIMC / 8); j += 512) {   // 49*48 = 2352 jobs
      const int n  = j % 49;          // lane-consecutive -> coalesced global reads
      const int c0 = (j / 49) * 8;
      union { bf16x8 v; __hip_bfloat16 h[8]; } u;
      #pragma unroll
      for (int k = 0; k < 8; ++k)
        u.h[k] = f2b(xg[(c0 + k) * 49 + n]);
      *(bf16x8*)&xs[n * 392 + c0] = u.v;   // 16B-aligned (392 % 8 == 0)
    }
  }
  __syncthreads();   // bar1

  // ---- PA: qin[nq][c] = dw3x3 s2 p1 (local_q) + avgpool2 (zero-padded)
  if (tid < DIMC) {
    const int c = tid;
    float xv[49];
    #pragma unroll
    for (int n = 0; n < 49; ++n) xv[n] = b2f(xs[n * 392 + c]);
    float wq[9];
    #pragma unroll
    for (int j = 0; j < 9; ++j) wq[j] = qlw[c * 9 + j];
    const float cb = qlb[c];
    #pragma unroll
    for (int oh = 0; oh < 4; ++oh) {
      #pragma unroll
      for (int ow = 0; ow < 4; ++ow) {
        float a = cb;
        #pragma unroll
        for (int kh = 0; kh < 3; ++kh) {
          const int ih = 2 * oh - 1 + kh;
          if (ih < 0 || ih > 6) continue;
          #pragma unroll
          for (int kwi = 0; kwi < 3; ++kwi) {
            const int iw = 2 * ow - 1 + kwi;
            if (iw < 0 || iw > 6) continue;
            a += wq[kh * 3 + kwi] * xv[ih * 7 + iw];
          }
        }
        if (oh < 3 && ow < 3)
          a += 0.25f * (xv[(2*oh)*7 + 2*ow] + xv[(2*oh)*7 + 2*ow + 1] +
                        xv[(2*oh+1)*7 + 2*ow] + xv[(2*oh+1)*7 + 2*ow + 1]);
        qin[(oh * 4 + ow) * 392 + c] = f2b(a);
      }
    }
  }
  __syncthreads();   // bar2

  // ================= MEGA phase: kGEMM + qGEMM + vGEMM(both halves) =================

  // -- k GEMM (128 ch): wave = M-tile, 4 N-tiles, K=384 -> kt
  {
    const int mt = wave;
    f32x4 acc[4];
    #pragma unroll
    for (int nt = 0; nt < 4; ++nt) acc[nt] = fzero();
    for (int ks = 0; ks < 12; ++ks) {
      const int c0 = ks * 32 + quad * 8;
      bf16x8 a = ld8(&kwb[(mt * 16 + l15) * DIMC + c0]);
      bf16x8 z[4];
      #pragma unroll
      for (int nt = 0; nt < 3; ++nt) z[nt] = ld8(&xs[(nt * 16 + l15) * 392 + c0]);
      z[3] = (l15 == 0) ? ld8(&xs[48 * 392 + c0]) : bzero();
      #pragma unroll
      for (int nt = 0; nt < 4; ++nt)
        acc[nt] = __builtin_amdgcn_mfma_f32_16x16x32_bf16(a, z[nt], acc[nt], 0, 0, 0);
    }
    #pragma unroll
    for (int r = 0; r < 4; ++r) {
      const int oc = mt * 16 + quad * 4 + r;
      float s, o;
      bn_so(kbn, NHKD, oc, kb[oc], s, o);
      #pragma unroll
      for (int nt = 0; nt < 4; ++nt) {
        const int n = nt * 16 + l15;
        if (n < 49) kt[n * 136 + oc] = f2b(acc[nt][r] * s + o);
        // rows 49..63 stale: only feed masked nk>=49 logit columns
      }
    }
  }

  // -- q GEMM -> qsm[h][nq][kd], zero kd 16..31 pad (A-frag pad!)
  {
    const int mt = wave;
    f32x4 acc = fzero();
    for (int ks = 0; ks < 12; ++ks) {
      const int c0 = ks * 32 + quad * 8;
      bf16x8 bv = ld8(&qin[l15 * 392 + c0]);
      bf16x8 av = ld8(&qpwb[(mt * 16 + l15) * DIMC + c0]);
      acc = __builtin_amdgcn_mfma_f32_16x16x32_bf16(av, bv, acc, 0, 0, 0);
    }
    #pragma unroll
    for (int r = 0; r < 4; ++r) {
      const int oc = mt * 16 + quad * 4 + r;
      float s, o;
      bn_so(qbn, NHKD, oc, qpb[oc], s, o);
      const int kd = oc & 15;
      qsm[wave * 640 + l15 * 40 + kd] = f2b(acc[r] * s + o);
      qsm[wave * 640 + l15 * 40 + kd + 16] = f2b(0.f);
    }
  }

  // -- v GEMM: wave owns ch {32w..32w+31} and {256+32w..+31}; acc in regs (64 VGPR)
  f32x4 va[2][2][4];   // [pass][mt][nt]
  #pragma unroll
  for (int p = 0; p < 2; ++p)
    #pragma unroll
    for (int mt = 0; mt < 2; ++mt)
      #pragma unroll
      for (int nt = 0; nt < 4; ++nt) va[p][mt][nt] = fzero();
  {
    const int chb = wave * 32;
    for (int ks = 0; ks < 12; ++ks) {
      const int c0 = ks * 32 + quad * 8;
      bf16x8 z[4];
      #pragma unroll
      for (int nt = 0; nt < 3; ++nt) z[nt] = ld8(&xs[(nt * 16 + l15) * 392 + c0]);
      z[3] = (l15 == 0) ? ld8(&xs[48 * 392 + c0]) : bzero();
      #pragma unroll
      for (int p = 0; p < 2; ++p) {
        #pragma unroll
        for (int mt = 0; mt < 2; ++mt) {
          bf16x8 a = ld8(&vwb[(p * 256 + chb + mt * 16 + l15) * DIMC + c0]);
          #pragma unroll
          for (int nt = 0; nt < 4; ++nt)
            va[p][mt][nt] = __builtin_amdgcn_mfma_f32_16x16x32_bf16(a, z[nt], va[p][mt][nt], 0, 0, 0);
        }
      }
    }
  }
  __syncthreads();   // bar3 — xs dead; kt/qsm ready

  // ---- write vsm pass 0 (own block, overlays xs — all xs reads drained at bar3)
  {
    __hip_bfloat16* vbw_ = vsm + wave * 2304;
    #pragma unroll
    for (int mt = 0; mt < 2; ++mt)
      #pragma unroll
      for (int r = 0; r < 4; ++r) {
        const int chl = mt * 16 + quad * 4 + r;
        const int gch = wave * 32 + chl;
        float s, o;
        bn_so(vbn, DHC, gch, vb[gch], s, o);
        #pragma unroll
        for (int nt = 0; nt < 4; ++nt)
          vbw_[chl * 72 + nt * 16 + l15] = f2b(va[0][mt][nt][r] * s + o);
      }
  }

  // ---- PD: QK^T*scale + bias, softmax -> attnS[h][nq][nk^] (XOR-swizzled)
  {
    const int h = wave;
    bf16x8 av = ld8(&qsm[h * 640 + l15 * 40 + quad * 8]);
    float p[4][4];
    #pragma unroll
    for (int t = 0; t < 4; ++t) {
      bf16x8 bv = bzero();
      if (quad < 2) bv = ld8(&kt[(t * 16 + l15) * 136 + h * 16 + quad * 8]);
      f32x4 lg = __builtin_amdgcn_mfma_f32_16x16x32_bf16(av, bv, fzero(), 0, 0, 0);
      #pragma unroll
      for (int r = 0; r < 4; ++r) {
        const int nq = quad * 4 + r;
        const int nk = t * 16 + l15;
        float val = -30000.f;
        if (nk < 49) val = lg[r] * 0.25f + ab[h * n_off + bidx[nq * 49 + nk]];
        p[t][r] = val;
      }
    }
    #pragma unroll
    for (int r = 0; r < 4; ++r) {
      float m = fmaxf(fmaxf(p[0][r], p[1][r]), fmaxf(p[2][r], p[3][r]));
      m = fmaxf(m, __shfl_xor(m, 1));
      m = fmaxf(m, __shfl_xor(m, 2));
      m = fmaxf(m, __shfl_xor(m, 4));
      m = fmaxf(m, __shfl_xor(m, 8));
      float e[4], sum = 0.f;
      #pragma unroll
      for (int t = 0; t < 4; ++t) { e[t] = __expf(p[t][r] - m); sum += e[t]; }
      sum += __shfl_xor(sum, 1);
      sum += __shfl_xor(sum, 2);
      sum += __shfl_xor(sum, 4);
      sum += __shfl_xor(sum, 8);
      const float inv = 1.f / sum;
      #pragma unroll
      for (int t = 0; t < 4; ++t) p[t][r] = e[t] * inv;   // exactly 0 for nk>=49
    }
    #pragma unroll
    for (int r = 0; r < 4; ++r) {
      const int nq = quad * 4 + r;
      #pragma unroll
      for (int t = 0; t < 4; ++t) {
        const int nk = t * 16 + l15;
        attnS[h * 1024 + nq * 64 + (nk ^ ((nq & 7) << 3))] = f2b(p[t][r]);
      }
    }
  }
  __syncthreads();   // bar4 — attnS ready; kt reads done (rout may overlay)

  // ================= v-path: wave-private, NO barriers =================
  #pragma unroll
  for (int p = 0; p < 2; ++p) {
    if (p == 1) {   // write vsm pass 1 into own block (pass-0 reads were same-wave)
      __hip_bfloat16* vbw_ = vsm + wave * 2304;
      #pragma unroll
      for (int mt = 0; mt < 2; ++mt)
        #pragma unroll
        for (int r = 0; r < 4; ++r) {
          const int chl = mt * 16 + quad * 4 + r;
          const int gch = 256 + wave * 32 + chl;
          float s, o;
          bn_so(vbn, DHC, gch, vb[gch], s, o);
          #pragma unroll
          for (int nt = 0; nt < 4; ++nt)
            vbw_[chl * 72 + nt * 16 + l15] = f2b(va[1][mt][nt][r] * s + o);
        }
    }

    // v_local: lane = (half, cl); cl = local channel, 8 positions per lane
    {
      const int cl   = lane & 31;
      const int half = lane >> 5;
      const int gch  = p * 256 + wave * 32 + cl;
      const __hip_bfloat16* vrow = vsm + wave * 2304 + cl * 72;
      float wv[9];
      #pragma unroll
      for (int j = 0; j < 9; ++j) wv[j] = vlw[gch * 9 + j];
      float s, o;
      bn_so(vlbn, DHC, gch, vlb[gch], s, o);
      #pragma unroll
      for (int pp = 0; pp < 8; ++pp) {
        const int pos = half * 8 + pp;
        const int oh = pos >> 2, ow = pos & 3;
        float a = 0.f;
        #pragma unroll
        for (int kh = 0; kh < 3; ++kh) {
          const int ih = 2 * oh - 1 + kh;
          if (ih < 0 || ih > 6) continue;
          #pragma unroll
          for (int kwi = 0; kwi < 3; ++kwi) {
            const int iw = 2 * ow - 1 + kwi;
            if (iw < 0 || iw > 6) continue;
            a += wv[kh * 3 + kwi] * b2f(vrow[ih * 7 + iw]);
          }
        }
        rout[pos * 520 + gch] = f2b(a * s + o);
      }
    }

    // PV (head h = 4p + w/2): 2 M-tiles; rout = relu(xa + vloc)
    {
      const int h = p * 4 + (wave >> 1);
      const __hip_bfloat16* vbw_ = vsm + wave * 2304;
      #pragma unroll
      for (int mt = 0; mt < 2; ++mt) {
        f32x4 acc = fzero();
        #pragma unroll
        for (int ks = 0; ks < 2; ++ks) {
          const int k0 = ks * 32 + quad * 8;
          bf16x8 av = ld8(&vbw_[(mt * 16 + l15) * 72 + k0]);           // A[ch][nk]
          bf16x8 bv = ld8(&attnS[h * 1024 + l15 * 64 + (k0 ^ ((l15 & 7) << 3))]); // B[nq][nk]
          acc = __builtin_amdgcn_mfma_f32_16x16x32_bf16(av, bv, acc, 0, 0, 0);
        }
        #pragma unroll
        for (int r = 0; r < 4; ++r) {
          const int gch = p * 256 + wave * 32 + mt * 16 + quad * 4 + r;
          const int ad = l15 * 520 + gch;
          const float val = acc[r] + b2f(rout[ad]);
          rout[ad] = f2b(fmaxf(val, 0.f));
        }
      }
    }
  }
  __syncthreads();   // bar5 — rout complete

  // ---- PF: proj GEMM — out = BN(pw @ rout + pb), fp32 store
  {
    const int mt0 = wave * 3;
    f32x4 acc[3];
    #pragma unroll
    for (int t = 0; t < 3; ++t) acc[t] = fzero();
    for (int ks = 0; ks < 16; ++ks) {
      const int c0 = ks * 32 + quad * 8;
      bf16x8 bv = ld8(&rout[l15 * 520 + c0]);
      #pragma unroll
      for (int t = 0; t < 3; ++t) {
        bf16x8 av = ld8(&pwb[((mt0 + t) * 16 + l15) * DHC + c0]);
        acc[t] = __builtin_amdgcn_mfma_f32_16x16x32_bf16(av, bv, acc[t], 0, 0, 0);
      }
    }
    float* outb = out + (size_t)b * (OUTC * 16);
    #pragma unroll
    for (int t = 0; t < 3; ++t) {
      #pragma unroll
      for (int r = 0; r < 4; ++r) {
        const int oc = (mt0 + t) * 16 + quad * 4 + r;
        float s, o;
        bn_so(pbn, OUTC, oc, pb[oc], s, o);
        outb[oc * 16 + l15] = acc[t][r] * s + o;
      }
    }
  }
}

extern "C" void kernel_launch(void* const* d_in, const int* in_sizes, int n_in,
                              void* d_out, int out_size, void* d_ws, size_t ws_size,
                              hipStream_t stream) {
  const float* x    = (const float*)d_in[0];
  const float* qlw  = (const float*)d_in[1];
  const float* qlb  = (const float*)d_in[2];
  const float* qpw  = (const float*)d_in[3];
  const float* qpb  = (const float*)d_in[4];
  const float* qbn  = (const float*)d_in[5];
  const float* kw   = (const float*)d_in[6];
  const float* kb   = (const float*)d_in[7];
  const float* kbn  = (const float*)d_in[8];
  const float* vw   = (const float*)d_in[9];
  const float* vb   = (const float*)d_in[10];
  const float* vbn  = (const float*)d_in[11];
  const float* vlw  = (const float*)d_in[12];
  const float* vlb  = (const float*)d_in[13];
  const float* vlbn = (const float*)d_in[14];
  const float* pw   = (const float*)d_in[15];
  const float* pb   = (const float*)d_in[16];
  const float* pbn  = (const float*)d_in[17];
  const float* ab   = (const float*)d_in[18];
  const int*   bidx = (const int*)d_in[19];
  const int n_off = in_sizes[18] / 8;
  const int Bn = in_sizes[0] / (DIMC * NPOS);   // 2048

  __hip_bfloat16* wsb = (__hip_bfloat16*)d_ws;  // 983,040 B used

  prep_weights<<<480, 256, 0, stream>>>(kw, vw, qpw, pw, wsb);
  attn4d_kernel<<<Bn, 512, 0, stream>>>(x, qlw, qlb, qpb, qbn, kb, kbn,
                                        vb, vbn, vlw, vlb, vlbn, pb, pbn,
                                        ab, bidx, wsb, n_off, (float*)d_out);
}